// Round 9
// baseline (3749.006 us; speedup 1.0000x reference)
//
#include <hip/hip_runtime.h>
#include <math.h>
#include <stdint.h>

// Problem constants
#define Bn 32
#define Sn 512
#define En 256
#define Hn 512
#define Ln 48
#define G4 2048   // 4*H
#define NWG 32    // workgroups per direction in lstm_rec
#define SENT16 0x7FFFu   // bf16 NaN — impossible for h = o*tanh(c), |h|<1

typedef unsigned short u16;
typedef __attribute__((ext_vector_type(8))) __bf16 bf16x8;
typedef __attribute__((ext_vector_type(4))) float f32x4;

__device__ inline float bf2f(u16 u) {
    return __uint_as_float(((unsigned)u) << 16);
}
__device__ inline u16 f2bf(float f) {
    unsigned u = __float_as_uint(f);
    unsigned r = (u + 0x7fffu + ((u >> 16) & 1u)) >> 16;  // RTNE
    return (u16)r;
}
__device__ inline float sigmoidf_(float x) { return 1.f / (1.f + expf(-x)); }
__device__ inline float tanh_fast(float x) { return 2.f / (1.f + expf(-2.f * x)) - 1.f; }

// any 16-bit field of the 4 dwords equals SENT16?
__device__ inline unsigned badMask(f32x4 v) {
    unsigned acc = 0;
    #pragma unroll
    for (int i = 0; i < 4; i++) {
        unsigned d = __float_as_uint(v[i]);
        unsigned x = d ^ 0x7FFF7FFFu;
        acc |= (x - 0x00010001u) & ~x & 0x80008000u;
    }
    return acc;
}

// ---------------------------------------------------------------------------
// prep: embed gather -> bf16 x, weight bf16 conversions, exp(T), zero accums,
// sentinel-fill h buffers
// ---------------------------------------------------------------------------
__global__ __launch_bounds__(256) void prep_kernel(
    const int* __restrict__ tokens, const float* __restrict__ embed,
    const float* __restrict__ wihf, const float* __restrict__ wihb,
    const float* __restrict__ whhf, const float* __restrict__ whhb,
    const float* __restrict__ wem, const float* __restrict__ trans,
    u16* __restrict__ xbf, u16* __restrict__ wihf_b, u16* __restrict__ wihb_b,
    u16* __restrict__ whhf_b, u16* __restrict__ whhb_b, u16* __restrict__ wem_b,
    float* __restrict__ expT, float* __restrict__ alphaAcc,
    float* __restrict__ realAcc, unsigned* __restrict__ hf32,
    unsigned* __restrict__ hb32)
{
    size_t idx = (size_t)blockIdx.x * blockDim.x + threadIdx.x;
    size_t stride = (size_t)gridDim.x * blockDim.x;
    for (size_t i = idx; i < (size_t)Bn * Sn * En; i += stride) {
        size_t n = i >> 8; int ee = (int)(i & 255);
        int tok = tokens[n];
        xbf[i] = f2bf(embed[(size_t)tok * En + ee]);
    }
    for (size_t i = idx; i < (size_t)G4 * En; i += stride) {
        wihf_b[i] = f2bf(wihf[i]); wihb_b[i] = f2bf(wihb[i]);
    }
    for (size_t i = idx; i < (size_t)G4 * Hn; i += stride) {
        whhf_b[i] = f2bf(whhf[i]); whhb_b[i] = f2bf(whhb[i]);
    }
    for (size_t i = idx; i < (size_t)Ln * 2 * Hn; i += stride) wem_b[i] = f2bf(wem[i]);
    for (size_t i = idx; i < (size_t)Ln * Ln; i += stride) expT[i] = expf(trans[i]);
    for (size_t i = idx; i < (size_t)Bn * Ln; i += stride) alphaAcc[i] = 0.f;
    for (size_t i = idx; i < (size_t)Bn; i += stride) realAcc[i] = 0.f;
    const unsigned sp = (SENT16 << 16) | SENT16;
    for (size_t i = idx; i < (size_t)Bn * Sn * Hn / 2; i += stride) {
        hf32[i] = sp; hb32[i] = sp;
    }
}

// ---------------------------------------------------------------------------
// gemm_xw: xw[dir][t][b][g] = x(b,t) . w_ih[g] + bias[g], bf16 MFMA, fp32 acc
// ---------------------------------------------------------------------------
__global__ __launch_bounds__(256) void gemm_xw(
    const u16* __restrict__ xbf, const u16* __restrict__ wihf_b,
    const u16* __restrict__ wihb_b, const float* __restrict__ bias_f,
    const float* __restrict__ bias_b, u16* __restrict__ xw_f, u16* __restrict__ xw_b)
{
    int mb = blockIdx.x, nb = blockIdx.y, dir = blockIdx.z;
    const u16* wih = dir ? wihb_b : wihf_b;
    const float* bias = dir ? bias_b : bias_f;
    u16* xw = dir ? xw_b : xw_f;

    __shared__ u16 At[64 * 136];
    __shared__ u16 Bt[64 * 136];

    int tid = threadIdx.x;
    int w = tid >> 6, lane = tid & 63;
    int lm = lane & 15, lkq = (lane >> 4) * 8;
    int Moff = (w & 1) * 32, Noff = (w >> 1) * 32;

    f32x4 zero = {0.f, 0.f, 0.f, 0.f};
    f32x4 acc[2][2] = {{zero, zero}, {zero, zero}};

    for (int kc = 0; kc < 2; kc++) {
        for (int c = tid; c < 1024; c += 256) {
            int r = c >> 4, cc = (c & 15) * 8;
            *(bf16x8*)&At[r * 136 + cc] =
                *(const bf16x8*)&xbf[((size_t)(mb * 64 + r)) * En + kc * 128 + cc];
            *(bf16x8*)&Bt[r * 136 + cc] =
                *(const bf16x8*)&wih[((size_t)(nb * 64 + r)) * En + kc * 128 + cc];
        }
        __syncthreads();
        #pragma unroll
        for (int ks = 0; ks < 4; ks++) {
            int k = ks * 32 + lkq;
            bf16x8 a0 = *(const bf16x8*)&At[(Moff + lm) * 136 + k];
            bf16x8 a1 = *(const bf16x8*)&At[(Moff + 16 + lm) * 136 + k];
            bf16x8 b0 = *(const bf16x8*)&Bt[(Noff + lm) * 136 + k];
            bf16x8 b1 = *(const bf16x8*)&Bt[(Noff + 16 + lm) * 136 + k];
            acc[0][0] = __builtin_amdgcn_mfma_f32_16x16x32_bf16(a0, b0, acc[0][0], 0, 0, 0);
            acc[0][1] = __builtin_amdgcn_mfma_f32_16x16x32_bf16(a0, b1, acc[0][1], 0, 0, 0);
            acc[1][0] = __builtin_amdgcn_mfma_f32_16x16x32_bf16(a1, b0, acc[1][0], 0, 0, 0);
            acc[1][1] = __builtin_amdgcn_mfma_f32_16x16x32_bf16(a1, b1, acc[1][1], 0, 0, 0);
        }
        __syncthreads();
    }
    #pragma unroll
    for (int mi = 0; mi < 2; mi++)
        #pragma unroll
        for (int ni = 0; ni < 2; ni++)
            #pragma unroll
            for (int reg = 0; reg < 4; reg++) {
                int row = Moff + mi * 16 + (lane >> 4) * 4 + reg;
                int col = Noff + ni * 16 + lm;
                int n = mb * 64 + row;          // n = b*512 + t
                int g = nb * 64 + col;
                int t = n & 511, b = n >> 9;
                float v = acc[mi][ni][reg] + bias[g];
                xw[((size_t)t * Bn + b) * G4 + g] = f2bf(v);
            }
}

// ---------------------------------------------------------------------------
// lstm_rec: 64 WGs (32/dir) x 512 thr, cooperative. h layout [t][b][k]
// (32 KB contiguous per step). Consumers load MFMA A-fragments DIRECTLY to
// registers (no LDS staging, no sync#1, no bank conflicts): 16x dwordx4 sc1
// off one base pointer, per-wave sentinel-retry. Each 16B fragment maps to
// exactly one producer 16B store, so per-fragment checks are sound.
// ---------------------------------------------------------------------------
__global__ __launch_bounds__(512) void lstm_rec(
    const u16* __restrict__ whhf_b, const u16* __restrict__ whhb_b,
    const u16* __restrict__ xw_f, const u16* __restrict__ xw_b,
    u16* __restrict__ hf, u16* __restrict__ hb)
{
    int wg = blockIdx.x;
    int dir = wg >> 5;
    int w = wg & 31;
    const u16* __restrict__ whh = dir ? whhb_b : whhf_b;
    const u16* __restrict__ xw  = dir ? xw_b  : xw_f;
    u16* __restrict__ hbuf = dir ? hb : hf;

    __shared__ float Cp[4 * 32 * 17];   // gate values [gate][batch][hcol]
    __shared__ u16 hout[32 * 16];

    int tid = threadIdx.x;
    int wv = tid >> 6, lane = tid & 63;
    int lm = lane & 15, kq = lane >> 4;
    int mt = wv & 1, nt = wv >> 1;       // wave -> (batch-tile, gate)
    int b = tid >> 4, hc = tid & 15;     // gate-phase roles

    // B fragments (w_hh rows for gate nt, hidden cols w*16..+16) in registers
    bf16x8 Bf[16];
    {
        const u16* wrow = &whh[((size_t)nt * Hn + (size_t)w * 16 + lm) * Hn];
        #pragma unroll
        for (int ks = 0; ks < 16; ks++)
            Bf[ks] = *(const bf16x8*)&wrow[ks * 32 + kq * 8];
    }

    float c_state = 0.f;
    const f32x4 zero = {0.f, 0.f, 0.f, 0.f};

    for (int it = 0; it < Sn; it++) {
        int t = dir ? (Sn - 1 - it) : it;
        f32x4 acc = zero;

        // xw gate inputs for (b, hc) — independent of h; in flight during poll
        const u16* xp = &xw[((size_t)t * Bn + b) * G4 + (size_t)w * 16 + hc];
        float xg0 = bf2f(xp[0 * Hn]);
        float xg1 = bf2f(xp[1 * Hn]);
        float xg2 = bf2f(xp[2 * Hn]);
        float xg3 = bf2f(xp[3 * Hn]);

        if (it > 0) {
            int tprev = dir ? (t + 1) : (t - 1);
            // A-fragment base for this lane: batch row (mt*16+lm), k = kq*8
            const u16* ab = &hbuf[((size_t)tprev * Bn + (size_t)(mt * 16 + lm)) * Hn + kq * 8];
            f32x4 A0, A1, A2, A3, A4, A5, A6, A7, A8, A9, A10, A11, A12, A13, A14, A15;
            int tries = 0;
            while (true) {
                asm volatile(
                    "global_load_dwordx4 %0, %16, off sc1\n\t"
                    "global_load_dwordx4 %1, %16, off offset:64 sc1\n\t"
                    "global_load_dwordx4 %2, %16, off offset:128 sc1\n\t"
                    "global_load_dwordx4 %3, %16, off offset:192 sc1\n\t"
                    "global_load_dwordx4 %4, %16, off offset:256 sc1\n\t"
                    "global_load_dwordx4 %5, %16, off offset:320 sc1\n\t"
                    "global_load_dwordx4 %6, %16, off offset:384 sc1\n\t"
                    "global_load_dwordx4 %7, %16, off offset:448 sc1\n\t"
                    "global_load_dwordx4 %8, %16, off offset:512 sc1\n\t"
                    "global_load_dwordx4 %9, %16, off offset:576 sc1\n\t"
                    "global_load_dwordx4 %10, %16, off offset:640 sc1\n\t"
                    "global_load_dwordx4 %11, %16, off offset:704 sc1\n\t"
                    "global_load_dwordx4 %12, %16, off offset:768 sc1\n\t"
                    "global_load_dwordx4 %13, %16, off offset:832 sc1\n\t"
                    "global_load_dwordx4 %14, %16, off offset:896 sc1\n\t"
                    "global_load_dwordx4 %15, %16, off offset:960 sc1\n\t"
                    "s_waitcnt vmcnt(0)"
                    : "=v"(A0), "=v"(A1), "=v"(A2), "=v"(A3),
                      "=v"(A4), "=v"(A5), "=v"(A6), "=v"(A7),
                      "=v"(A8), "=v"(A9), "=v"(A10), "=v"(A11),
                      "=v"(A12), "=v"(A13), "=v"(A14), "=v"(A15)
                    : "v"(ab) : "memory");
                unsigned bad = badMask(A0) | badMask(A1) | badMask(A2) | badMask(A3)
                             | badMask(A4) | badMask(A5) | badMask(A6) | badMask(A7)
                             | badMask(A8) | badMask(A9) | badMask(A10) | badMask(A11)
                             | badMask(A12) | badMask(A13) | badMask(A14) | badMask(A15);
                if (!bad) break;
                if (++tries > (1 << 16)) break;   // fail-safe: never hang
            }
            f32x4 aa = zero, ab2 = zero;
            aa  = __builtin_amdgcn_mfma_f32_16x16x32_bf16(*(bf16x8*)&A0,  Bf[0],  aa,  0, 0, 0);
            ab2 = __builtin_amdgcn_mfma_f32_16x16x32_bf16(*(bf16x8*)&A1,  Bf[1],  ab2, 0, 0, 0);
            aa  = __builtin_amdgcn_mfma_f32_16x16x32_bf16(*(bf16x8*)&A2,  Bf[2],  aa,  0, 0, 0);
            ab2 = __builtin_amdgcn_mfma_f32_16x16x32_bf16(*(bf16x8*)&A3,  Bf[3],  ab2, 0, 0, 0);
            aa  = __builtin_amdgcn_mfma_f32_16x16x32_bf16(*(bf16x8*)&A4,  Bf[4],  aa,  0, 0, 0);
            ab2 = __builtin_amdgcn_mfma_f32_16x16x32_bf16(*(bf16x8*)&A5,  Bf[5],  ab2, 0, 0, 0);
            aa  = __builtin_amdgcn_mfma_f32_16x16x32_bf16(*(bf16x8*)&A6,  Bf[6],  aa,  0, 0, 0);
            ab2 = __builtin_amdgcn_mfma_f32_16x16x32_bf16(*(bf16x8*)&A7,  Bf[7],  ab2, 0, 0, 0);
            aa  = __builtin_amdgcn_mfma_f32_16x16x32_bf16(*(bf16x8*)&A8,  Bf[8],  aa,  0, 0, 0);
            ab2 = __builtin_amdgcn_mfma_f32_16x16x32_bf16(*(bf16x8*)&A9,  Bf[9],  ab2, 0, 0, 0);
            aa  = __builtin_amdgcn_mfma_f32_16x16x32_bf16(*(bf16x8*)&A10, Bf[10], aa,  0, 0, 0);
            ab2 = __builtin_amdgcn_mfma_f32_16x16x32_bf16(*(bf16x8*)&A11, Bf[11], ab2, 0, 0, 0);
            aa  = __builtin_amdgcn_mfma_f32_16x16x32_bf16(*(bf16x8*)&A12, Bf[12], aa,  0, 0, 0);
            ab2 = __builtin_amdgcn_mfma_f32_16x16x32_bf16(*(bf16x8*)&A13, Bf[13], ab2, 0, 0, 0);
            aa  = __builtin_amdgcn_mfma_f32_16x16x32_bf16(*(bf16x8*)&A14, Bf[14], aa,  0, 0, 0);
            ab2 = __builtin_amdgcn_mfma_f32_16x16x32_bf16(*(bf16x8*)&A15, Bf[15], ab2, 0, 0, 0);
            acc = aa + ab2;
        }

        #pragma unroll
        for (int reg = 0; reg < 4; reg++)
            Cp[(nt * 32 + mt * 16 + kq * 4 + reg) * 17 + lm] = acc[reg];
        __syncthreads();                                  // sync #2

        float g0 = Cp[(0 * 32 + b) * 17 + hc] + xg0;
        float g1 = Cp[(1 * 32 + b) * 17 + hc] + xg1;
        float g2 = Cp[(2 * 32 + b) * 17 + hc] + xg2;
        float g3 = Cp[(3 * 32 + b) * 17 + hc] + xg3;
        float i_ = sigmoidf_(g0);
        float f_ = sigmoidf_(g1);
        float gg = tanh_fast(g2);
        float o_ = sigmoidf_(g3);
        c_state = f_ * c_state + i_ * gg;
        float hv = o_ * tanh_fast(c_state);
        hout[tid] = f2bf(hv);
        __syncthreads();                                  // sync #3

        if (tid < 64) {
            int bq = lane >> 1, half = lane & 1;
            f32x4 hv8 = *(const f32x4*)&hout[lane * 8];
            u16* sp = &hbuf[((size_t)t * Bn + bq) * Hn + (size_t)w * 16 + half * 8];
            asm volatile("global_store_dwordx4 %0, %1, off sc1"
                         :: "v"(sp), "v"(hv8) : "memory");
        }
    }
}

// ---------------------------------------------------------------------------
// emis: e[b,t,l] = exp( [hf|hb](b,t) . w_em[l] + b_em[l] ), bf16 MFMA.
// h layout is [t][b][k]: linear row r = t*Bn + b, so A loads are unchanged;
// only the C-store decode (b = r&31, t = r>>5) differs.
// ---------------------------------------------------------------------------
__global__ __launch_bounds__(256) void emis(
    const u16* __restrict__ hf, const u16* __restrict__ hb,
    const u16* __restrict__ wem_b, const float* __restrict__ bem,
    float* __restrict__ e)
{
    int mb = blockIdx.x;
    int tid = threadIdx.x, wv = tid >> 6, lane = tid & 63;
    int lm = lane & 15, lkq = (lane >> 4) * 8;
    int row = mb * 64 + wv * 16;

    f32x4 zero = {0.f, 0.f, 0.f, 0.f};
    f32x4 acc[3] = {zero, zero, zero};
    for (int ks = 0; ks < 32; ks++) {
        int k = ks * 32 + lkq;
        const u16* hsrc = (ks < 16) ? &hf[(size_t)(row + lm) * Hn + k]
                                    : &hb[(size_t)(row + lm) * Hn + (k - 512)];
        bf16x8 a = *(const bf16x8*)hsrc;
        #pragma unroll
        for (int nt = 0; nt < 3; nt++) {
            bf16x8 bfr = *(const bf16x8*)&wem_b[(size_t)(nt * 16 + lm) * 1024 + k];
            acc[nt] = __builtin_amdgcn_mfma_f32_16x16x32_bf16(a, bfr, acc[nt], 0, 0, 0);
        }
    }
    #pragma unroll
    for (int nt = 0; nt < 3; nt++)
        #pragma unroll
        for (int reg = 0; reg < 4; reg++) {
            int r = row + (lane >> 4) * 4 + reg;   // r = t*Bn + b
            int col = nt * 16 + lm;
            int bb = r & 31, tt = r >> 5;
            float lg = acc[nt][reg] + bem[col];
            e[(((size_t)bb << 9) + tt) * Ln + col] = expf(lg);
        }
}

// ---------------------------------------------------------------------------
// crf_step / finalize
// ---------------------------------------------------------------------------
__global__ __launch_bounds__(64) void crf_step(
    const float* __restrict__ e, const float* __restrict__ expT,
    const int* __restrict__ labels, const int* __restrict__ lengths,
    float* __restrict__ alphaAcc, float* __restrict__ realAcc)
{
    int bt = blockIdx.x;
    int b = bt >> 9, t = bt & 511;
    __shared__ float er[Ln];
    int tid = threadIdx.x;
    if (tid < Ln) er[tid] = e[(size_t)bt * Ln + tid];
    __syncthreads();
    bool inlen = t < lengths[b];
    if (t >= 1 && inlen && tid < Ln) {
        int i = tid;
        float m = -1e30f;
        for (int j = 0; j < Ln; j++) m = fmaxf(m, expT[i * Ln + j] + er[j]);
        float s = 0.f;
        for (int j = 0; j < Ln; j++) s += expf(expT[i * Ln + j] + er[j] - m);
        atomicAdd(&alphaAcc[b * Ln + i], m + logf(s));
    }
    if (tid == 0 && inlen) {
        int lab = labels[b * Sn + t];
        float r = er[lab];
        if (t >= 1) r += expT[labels[b * Sn + t - 1] * Ln + lab];
        atomicAdd(&realAcc[b], r);
    }
}

__global__ __launch_bounds__(64) void finalize(
    const float* __restrict__ e, const float* __restrict__ alphaAcc,
    const float* __restrict__ realAcc, float* __restrict__ out)
{
    int b = threadIdx.x;
    if (b >= Bn) return;
    float m = -1e30f;
    for (int i = 0; i < Ln; i++) {
        float a = e[((size_t)b * Sn) * Ln + i] + alphaAcc[b * Ln + i];
        m = fmaxf(m, a);
    }
    float s = 0.f;
    for (int i = 0; i < Ln; i++) {
        float a = e[((size_t)b * Sn) * Ln + i] + alphaAcc[b * Ln + i];
        s += expf(a - m);
    }
    out[b] = m + logf(s) - realAcc[b];
}

// ---------------------------------------------------------------------------
extern "C" void kernel_launch(void* const* d_in, const int* in_sizes, int n_in,
                              void* d_out, int out_size, void* d_ws, size_t ws_size,
                              hipStream_t stream)
{
    const int*   tokens = (const int*)d_in[0];
    const int*   length = (const int*)d_in[1];
    const int*   labels = (const int*)d_in[2];
    const float* embed  = (const float*)d_in[3];
    const float* wihf   = (const float*)d_in[4];
    const float* whhf   = (const float*)d_in[5];
    const float* bf     = (const float*)d_in[6];
    const float* wihb   = (const float*)d_in[7];
    const float* whhb   = (const float*)d_in[8];
    const float* bbv    = (const float*)d_in[9];
    const float* wem    = (const float*)d_in[10];
    const float* bem    = (const float*)d_in[11];
    const float* trans  = (const float*)d_in[12];
    float* out = (float*)d_out;

    char* p = (char*)d_ws;
    auto take = [&](size_t bytes) -> char* {
        char* q = p;
        p += (bytes + 255) & ~(size_t)255;
        return q;
    };
    u16* xw_f   = (u16*)take((size_t)Sn * Bn * G4 * 2);   // 64 MB
    u16* xw_b   = (u16*)take((size_t)Sn * Bn * G4 * 2);   // 64 MB
    u16* hf     = (u16*)take((size_t)Bn * Sn * Hn * 2);   // 16 MB, layout [t][b][k]
    u16* hb     = (u16*)take((size_t)Bn * Sn * Hn * 2);   // 16 MB, layout [t][b][k]
    u16* xbf    = (u16*)take((size_t)Bn * Sn * En * 2);   // 8 MB
    u16* wihf_b = (u16*)take((size_t)G4 * En * 2);
    u16* wihb_b = (u16*)take((size_t)G4 * En * 2);
    u16* whhf_b = (u16*)take((size_t)G4 * Hn * 2);
    u16* whhb_b = (u16*)take((size_t)G4 * Hn * 2);
    u16* wem_b  = (u16*)take((size_t)Ln * 2 * Hn * 2);
    float* e        = (float*)take((size_t)Bn * Sn * Ln * 4);
    float* expT     = (float*)take((size_t)Ln * Ln * 4);
    float* alphaAcc = (float*)take((size_t)Bn * Ln * 4);
    float* realAcc  = (float*)take((size_t)Bn * 4);
    if ((size_t)(p - (char*)d_ws) > ws_size) return;

    prep_kernel<<<4096, 256, 0, stream>>>(tokens, embed, wihf, wihb, whhf, whhb, wem, trans,
                                          xbf, wihf_b, wihb_b, whhf_b, whhb_b, wem_b,
                                          expT, alphaAcc, realAcc,
                                          (unsigned*)hf, (unsigned*)hb);

    dim3 g1(256, 32, 2);
    gemm_xw<<<g1, 256, 0, stream>>>(xbf, wihf_b, wihb_b, bf, bbv, xw_f, xw_b);

    void* ra[] = { (void*)&whhf_b, (void*)&whhb_b, (void*)&xw_f, (void*)&xw_b,
                   (void*)&hf, (void*)&hb };
    hipLaunchCooperativeKernel((const void*)lstm_rec, dim3(2 * NWG), dim3(512), ra, 0, stream);

    emis<<<256, 256, 0, stream>>>(hf, hb, wem_b, bem, e);
    crf_step<<<Bn * Sn, 64, 0, stream>>>(e, expT, labels, length, alphaAcc, realAcc);
    finalize<<<1, 64, 0, stream>>>(e, alphaAcc, realAcc, out);
}

// Round 10
// 1917.802 us; speedup vs baseline: 1.9548x; 1.9548x over previous
//
#include <hip/hip_runtime.h>
#include <math.h>
#include <stdint.h>

// Problem constants
#define Bn 32
#define Sn 512
#define En 256
#define Hn 512
#define Ln 48
#define G4 2048   // 4*H
#define NWG 16    // workgroups per direction in lstm_rec (32 hidden cols each)
#define SENT16 0x7FFFu   // bf16 NaN — impossible for h = o*tanh(c), |h|<1

typedef unsigned short u16;
typedef __attribute__((ext_vector_type(8))) __bf16 bf16x8;
typedef __attribute__((ext_vector_type(4))) float f32x4;

__device__ inline float bf2f(u16 u) {
    return __uint_as_float(((unsigned)u) << 16);
}
__device__ inline u16 f2bf(float f) {
    unsigned u = __float_as_uint(f);
    unsigned r = (u + 0x7fffu + ((u >> 16) & 1u)) >> 16;  // RTNE
    return (u16)r;
}
__device__ inline float sigmoidf_(float x) { return 1.f / (1.f + expf(-x)); }
__device__ inline float tanh_fast(float x) { return 2.f / (1.f + expf(-2.f * x)) - 1.f; }

// any 16-bit field of the 4 dwords equals SENT16?
__device__ inline unsigned badMask(f32x4 v) {
    unsigned acc = 0;
    #pragma unroll
    for (int i = 0; i < 4; i++) {
        unsigned d = __float_as_uint(v[i]);
        unsigned x = d ^ 0x7FFF7FFFu;
        acc |= (x - 0x00010001u) & ~x & 0x80008000u;
    }
    return acc;
}

// ---------------------------------------------------------------------------
// prep: embed gather -> bf16 x, weight bf16 conversions, exp(T), zero accums,
// sentinel-fill h buffers
// ---------------------------------------------------------------------------
__global__ __launch_bounds__(256) void prep_kernel(
    const int* __restrict__ tokens, const float* __restrict__ embed,
    const float* __restrict__ wihf, const float* __restrict__ wihb,
    const float* __restrict__ whhf, const float* __restrict__ whhb,
    const float* __restrict__ wem, const float* __restrict__ trans,
    u16* __restrict__ xbf, u16* __restrict__ wihf_b, u16* __restrict__ wihb_b,
    u16* __restrict__ whhf_b, u16* __restrict__ whhb_b, u16* __restrict__ wem_b,
    float* __restrict__ expT, float* __restrict__ alphaAcc,
    float* __restrict__ realAcc, unsigned* __restrict__ hf32,
    unsigned* __restrict__ hb32)
{
    size_t idx = (size_t)blockIdx.x * blockDim.x + threadIdx.x;
    size_t stride = (size_t)gridDim.x * blockDim.x;
    for (size_t i = idx; i < (size_t)Bn * Sn * En; i += stride) {
        size_t n = i >> 8; int ee = (int)(i & 255);
        int tok = tokens[n];
        xbf[i] = f2bf(embed[(size_t)tok * En + ee]);
    }
    for (size_t i = idx; i < (size_t)G4 * En; i += stride) {
        wihf_b[i] = f2bf(wihf[i]); wihb_b[i] = f2bf(wihb[i]);
    }
    for (size_t i = idx; i < (size_t)G4 * Hn; i += stride) {
        whhf_b[i] = f2bf(whhf[i]); whhb_b[i] = f2bf(whhb[i]);
    }
    for (size_t i = idx; i < (size_t)Ln * 2 * Hn; i += stride) wem_b[i] = f2bf(wem[i]);
    for (size_t i = idx; i < (size_t)Ln * Ln; i += stride) expT[i] = expf(trans[i]);
    for (size_t i = idx; i < (size_t)Bn * Ln; i += stride) alphaAcc[i] = 0.f;
    for (size_t i = idx; i < (size_t)Bn; i += stride) realAcc[i] = 0.f;
    const unsigned sp = (SENT16 << 16) | SENT16;
    for (size_t i = idx; i < (size_t)Bn * Sn * Hn / 2; i += stride) {
        hf32[i] = sp; hb32[i] = sp;
    }
}

// ---------------------------------------------------------------------------
// gemm_xw: xw[dir][t][b][g] = x(b,t) . w_ih[g] + bias[g], bf16 MFMA, fp32 acc
// ---------------------------------------------------------------------------
__global__ __launch_bounds__(256) void gemm_xw(
    const u16* __restrict__ xbf, const u16* __restrict__ wihf_b,
    const u16* __restrict__ wihb_b, const float* __restrict__ bias_f,
    const float* __restrict__ bias_b, u16* __restrict__ xw_f, u16* __restrict__ xw_b)
{
    int mb = blockIdx.x, nb = blockIdx.y, dir = blockIdx.z;
    const u16* wih = dir ? wihb_b : wihf_b;
    const float* bias = dir ? bias_b : bias_f;
    u16* xw = dir ? xw_b : xw_f;

    __shared__ u16 At[64 * 136];
    __shared__ u16 Bt[64 * 136];

    int tid = threadIdx.x;
    int w = tid >> 6, lane = tid & 63;
    int lm = lane & 15, lkq = (lane >> 4) * 8;
    int Moff = (w & 1) * 32, Noff = (w >> 1) * 32;

    f32x4 zero = {0.f, 0.f, 0.f, 0.f};
    f32x4 acc[2][2] = {{zero, zero}, {zero, zero}};

    for (int kc = 0; kc < 2; kc++) {
        for (int c = tid; c < 1024; c += 256) {
            int r = c >> 4, cc = (c & 15) * 8;
            *(bf16x8*)&At[r * 136 + cc] =
                *(const bf16x8*)&xbf[((size_t)(mb * 64 + r)) * En + kc * 128 + cc];
            *(bf16x8*)&Bt[r * 136 + cc] =
                *(const bf16x8*)&wih[((size_t)(nb * 64 + r)) * En + kc * 128 + cc];
        }
        __syncthreads();
        #pragma unroll
        for (int ks = 0; ks < 4; ks++) {
            int k = ks * 32 + lkq;
            bf16x8 a0 = *(const bf16x8*)&At[(Moff + lm) * 136 + k];
            bf16x8 a1 = *(const bf16x8*)&At[(Moff + 16 + lm) * 136 + k];
            bf16x8 b0 = *(const bf16x8*)&Bt[(Noff + lm) * 136 + k];
            bf16x8 b1 = *(const bf16x8*)&Bt[(Noff + 16 + lm) * 136 + k];
            acc[0][0] = __builtin_amdgcn_mfma_f32_16x16x32_bf16(a0, b0, acc[0][0], 0, 0, 0);
            acc[0][1] = __builtin_amdgcn_mfma_f32_16x16x32_bf16(a0, b1, acc[0][1], 0, 0, 0);
            acc[1][0] = __builtin_amdgcn_mfma_f32_16x16x32_bf16(a1, b0, acc[1][0], 0, 0, 0);
            acc[1][1] = __builtin_amdgcn_mfma_f32_16x16x32_bf16(a1, b1, acc[1][1], 0, 0, 0);
        }
        __syncthreads();
    }
    #pragma unroll
    for (int mi = 0; mi < 2; mi++)
        #pragma unroll
        for (int ni = 0; ni < 2; ni++)
            #pragma unroll
            for (int reg = 0; reg < 4; reg++) {
                int row = Moff + mi * 16 + (lane >> 4) * 4 + reg;
                int col = Noff + ni * 16 + lm;
                int n = mb * 64 + row;          // n = b*512 + t
                int g = nb * 64 + col;
                int t = n & 511, b = n >> 9;
                float v = acc[mi][ni][reg] + bias[g];
                xw[((size_t)t * Bn + b) * G4 + g] = f2bf(v);
            }
}

// ---------------------------------------------------------------------------
// lstm_rec: 32 WGs (16/dir) x 512 thr, cooperative. R8 protocol verbatim
// (sc1 device-scope data-poll, sentinel retry, LDS staging, batched stores)
// but 32 hidden cols per WG: halves consumer fan-out at the MALL (16x line
// re-request instead of 32x) and halves the straggler set.
// ---------------------------------------------------------------------------
__global__ __launch_bounds__(512) void lstm_rec(
    const u16* __restrict__ whhf_b, const u16* __restrict__ whhb_b,
    const u16* __restrict__ xw_f, const u16* __restrict__ xw_b,
    u16* __restrict__ hf, u16* __restrict__ hb)
{
    int wg = blockIdx.x;
    int dir = wg >> 4;
    int w = wg & 15;
    const u16* __restrict__ whh = dir ? whhb_b : whhf_b;
    const u16* __restrict__ xw  = dir ? xw_b  : xw_f;
    u16* __restrict__ hbuf = dir ? hb : hf;

    __shared__ u16 Hs[32 * 512];        // h_{t-1} staged, XOR-swizzled chunks
    __shared__ float Cp[4 * 32 * 33];   // gate values [gate][batch][32 cols pad 33]
    __shared__ u16 hout[32 * 32];       // h out [batch][32 cols]

    int tid = threadIdx.x;
    int wv = tid >> 6, lane = tid & 63;
    int lm = lane & 15, kq = lane >> 4;
    int mt = wv & 1, nt = wv >> 1;       // wave -> (batch-tile, gate)
    int b = tid >> 4, hc = tid & 15;     // gate-phase / staging roles

    // B fragments for BOTH 16-col N-tiles (gate nt, cols w*32 .. w*32+32)
    bf16x8 Bf0[16], Bf1[16];
    {
        const u16* wrow0 = &whh[((size_t)nt * Hn + (size_t)w * 32 + lm) * Hn];
        const u16* wrow1 = &whh[((size_t)nt * Hn + (size_t)w * 32 + 16 + lm) * Hn];
        #pragma unroll
        for (int ks = 0; ks < 16; ks++) {
            Bf0[ks] = *(const bf16x8*)&wrow0[ks * 32 + kq * 8];
            Bf1[ks] = *(const bf16x8*)&wrow1[ks * 32 + kq * 8];
        }
    }

    float cs0 = 0.f, cs1 = 0.f;   // c-state for cols hc and hc+16
    const f32x4 zero = {0.f, 0.f, 0.f, 0.f};

    for (int it = 0; it < Sn; it++) {
        int t = dir ? (Sn - 1 - it) : it;
        f32x4 acc0 = zero, acc1 = zero;

        // xw gate inputs for (b, hc) and (b, hc+16) — issue before the poll
        const u16* xp = &xw[((size_t)t * Bn + b) * G4 + (size_t)w * 32 + hc];
        float xgA0 = bf2f(xp[0 * Hn]),      xgB0 = bf2f(xp[0 * Hn + 16]);
        float xgA1 = bf2f(xp[1 * Hn]),      xgB1 = bf2f(xp[1 * Hn + 16]);
        float xgA2 = bf2f(xp[2 * Hn]),      xgB2 = bf2f(xp[2 * Hn + 16]);
        float xgA3 = bf2f(xp[3 * Hn]),      xgB3 = bf2f(xp[3 * Hn + 16]);

        if (it > 0) {
            int tprev = dir ? (t + 1) : (t - 1);
            const u16* base = &hbuf[((size_t)b * Sn + tprev) * Hn];
            const u16* p0 = base + (hc + 0) * 8;
            const u16* p1 = base + (hc + 16) * 8;
            const u16* p2 = base + (hc + 32) * 8;
            const u16* p3 = base + (hc + 48) * 8;
            f32x4 h0, h1, h2, h3;
            int tries = 0;
            while (true) {
                asm volatile(
                    "global_load_dwordx4 %0, %4, off sc1\n\t"
                    "global_load_dwordx4 %1, %5, off sc1\n\t"
                    "global_load_dwordx4 %2, %6, off sc1\n\t"
                    "global_load_dwordx4 %3, %7, off sc1\n\t"
                    "s_waitcnt vmcnt(0)"
                    : "=v"(h0), "=v"(h1), "=v"(h2), "=v"(h3)
                    : "v"(p0), "v"(p1), "v"(p2), "v"(p3)
                    : "memory");
                if (!(badMask(h0) | badMask(h1) | badMask(h2) | badMask(h3))) break;
                if (++tries > (1 << 16)) break;   // fail-safe: never hang
            }
            *(f32x4*)&Hs[(b * 64 + ((hc + 0) ^ (b & 7))) * 8] = h0;
            *(f32x4*)&Hs[(b * 64 + ((hc + 16) ^ (b & 7))) * 8] = h1;
            *(f32x4*)&Hs[(b * 64 + ((hc + 32) ^ (b & 7))) * 8] = h2;
            *(f32x4*)&Hs[(b * 64 + ((hc + 48) ^ (b & 7))) * 8] = h3;
            __syncthreads();                              // sync #1

            f32x4 aa0 = zero, ab0 = zero, aa1 = zero, ab1 = zero;
            #pragma unroll
            for (int ks2 = 0; ks2 < 8; ks2++) {
                bf16x8 a0 = *(const bf16x8*)
                    &Hs[((mt * 16 + lm) * 64 + (((2 * ks2) * 4 + kq) ^ (lm & 7))) * 8];
                aa0 = __builtin_amdgcn_mfma_f32_16x16x32_bf16(a0, Bf0[2 * ks2], aa0, 0, 0, 0);
                aa1 = __builtin_amdgcn_mfma_f32_16x16x32_bf16(a0, Bf1[2 * ks2], aa1, 0, 0, 0);
                bf16x8 a1 = *(const bf16x8*)
                    &Hs[((mt * 16 + lm) * 64 + (((2 * ks2 + 1) * 4 + kq) ^ (lm & 7))) * 8];
                ab0 = __builtin_amdgcn_mfma_f32_16x16x32_bf16(a1, Bf0[2 * ks2 + 1], ab0, 0, 0, 0);
                ab1 = __builtin_amdgcn_mfma_f32_16x16x32_bf16(a1, Bf1[2 * ks2 + 1], ab1, 0, 0, 0);
            }
            acc0 = aa0 + ab0;
            acc1 = aa1 + ab1;
        }

        #pragma unroll
        for (int reg = 0; reg < 4; reg++) {
            int r = (nt * 32 + mt * 16 + kq * 4 + reg) * 33;
            Cp[r + lm] = acc0[reg];
            Cp[r + 16 + lm] = acc1[reg];
        }
        __syncthreads();                                  // sync #2

        // gates for (b, hc) and (b, hc+16)
        float gA0 = Cp[(0 * 32 + b) * 33 + hc] + xgA0;
        float gA1 = Cp[(1 * 32 + b) * 33 + hc] + xgA1;
        float gA2 = Cp[(2 * 32 + b) * 33 + hc] + xgA2;
        float gA3 = Cp[(3 * 32 + b) * 33 + hc] + xgA3;
        float gB0 = Cp[(0 * 32 + b) * 33 + 16 + hc] + xgB0;
        float gB1 = Cp[(1 * 32 + b) * 33 + 16 + hc] + xgB1;
        float gB2 = Cp[(2 * 32 + b) * 33 + 16 + hc] + xgB2;
        float gB3 = Cp[(3 * 32 + b) * 33 + 16 + hc] + xgB3;
        float iA = sigmoidf_(gA0), fA = sigmoidf_(gA1);
        float gA = tanh_fast(gA2), oA = sigmoidf_(gA3);
        cs0 = fA * cs0 + iA * gA;
        float hvA = oA * tanh_fast(cs0);
        float iB = sigmoidf_(gB0), fB = sigmoidf_(gB1);
        float gB = tanh_fast(gB2), oB = sigmoidf_(gB3);
        cs1 = fB * cs1 + iB * gB;
        float hvB = oB * tanh_fast(cs1);
        hout[b * 32 + hc] = f2bf(hvA);
        hout[b * 32 + 16 + hc] = f2bf(hvB);
        __syncthreads();                                  // sync #3

        if (tid < 128) {
            int bq = tid >> 2, part = tid & 3;
            f32x4 hv8 = *(const f32x4*)&hout[bq * 32 + part * 8];
            u16* sp = &hbuf[((size_t)bq * Sn + t) * Hn + (size_t)w * 32 + part * 8];
            asm volatile("global_store_dwordx4 %0, %1, off sc1"
                         :: "v"(sp), "v"(hv8) : "memory");
        }
    }
}

// ---------------------------------------------------------------------------
// emis: e[b,t,l] = exp( [hf|hb](b,t) . w_em[l] + b_em[l] ), bf16 MFMA
// ---------------------------------------------------------------------------
__global__ __launch_bounds__(256) void emis(
    const u16* __restrict__ hf, const u16* __restrict__ hb,
    const u16* __restrict__ wem_b, const float* __restrict__ bem,
    float* __restrict__ e)
{
    int mb = blockIdx.x;
    int tid = threadIdx.x, wv = tid >> 6, lane = tid & 63;
    int lm = lane & 15, lkq = (lane >> 4) * 8;
    int row = mb * 64 + wv * 16;

    f32x4 zero = {0.f, 0.f, 0.f, 0.f};
    f32x4 acc[3] = {zero, zero, zero};
    for (int ks = 0; ks < 32; ks++) {
        int k = ks * 32 + lkq;
        const u16* hsrc = (ks < 16) ? &hf[(size_t)(row + lm) * Hn + k]
                                    : &hb[(size_t)(row + lm) * Hn + (k - 512)];
        bf16x8 a = *(const bf16x8*)hsrc;
        #pragma unroll
        for (int nt = 0; nt < 3; nt++) {
            bf16x8 bfr = *(const bf16x8*)&wem_b[(size_t)(nt * 16 + lm) * 1024 + k];
            acc[nt] = __builtin_amdgcn_mfma_f32_16x16x32_bf16(a, bfr, acc[nt], 0, 0, 0);
        }
    }
    #pragma unroll
    for (int nt = 0; nt < 3; nt++)
        #pragma unroll
        for (int reg = 0; reg < 4; reg++) {
            int r = row + (lane >> 4) * 4 + reg;
            int col = nt * 16 + lm;
            float lg = acc[nt][reg] + bem[col];
            e[(size_t)r * Ln + col] = expf(lg);
        }
}

// ---------------------------------------------------------------------------
// crf_step / finalize
// ---------------------------------------------------------------------------
__global__ __launch_bounds__(64) void crf_step(
    const float* __restrict__ e, const float* __restrict__ expT,
    const int* __restrict__ labels, const int* __restrict__ lengths,
    float* __restrict__ alphaAcc, float* __restrict__ realAcc)
{
    int bt = blockIdx.x;
    int b = bt >> 9, t = bt & 511;
    __shared__ float er[Ln];
    int tid = threadIdx.x;
    if (tid < Ln) er[tid] = e[(size_t)bt * Ln + tid];
    __syncthreads();
    bool inlen = t < lengths[b];
    if (t >= 1 && inlen && tid < Ln) {
        int i = tid;
        float m = -1e30f;
        for (int j = 0; j < Ln; j++) m = fmaxf(m, expT[i * Ln + j] + er[j]);
        float s = 0.f;
        for (int j = 0; j < Ln; j++) s += expf(expT[i * Ln + j] + er[j] - m);
        atomicAdd(&alphaAcc[b * Ln + i], m + logf(s));
    }
    if (tid == 0 && inlen) {
        int lab = labels[b * Sn + t];
        float r = er[lab];
        if (t >= 1) r += expT[labels[b * Sn + t - 1] * Ln + lab];
        atomicAdd(&realAcc[b], r);
    }
}

__global__ __launch_bounds__(64) void finalize(
    const float* __restrict__ e, const float* __restrict__ alphaAcc,
    const float* __restrict__ realAcc, float* __restrict__ out)
{
    int b = threadIdx.x;
    if (b >= Bn) return;
    float m = -1e30f;
    for (int i = 0; i < Ln; i++) {
        float a = e[((size_t)b * Sn) * Ln + i] + alphaAcc[b * Ln + i];
        m = fmaxf(m, a);
    }
    float s = 0.f;
    for (int i = 0; i < Ln; i++) {
        float a = e[((size_t)b * Sn) * Ln + i] + alphaAcc[b * Ln + i];
        s += expf(a - m);
    }
    out[b] = m + logf(s) - realAcc[b];
}

// ---------------------------------------------------------------------------
extern "C" void kernel_launch(void* const* d_in, const int* in_sizes, int n_in,
                              void* d_out, int out_size, void* d_ws, size_t ws_size,
                              hipStream_t stream)
{
    const int*   tokens = (const int*)d_in[0];
    const int*   length = (const int*)d_in[1];
    const int*   labels = (const int*)d_in[2];
    const float* embed  = (const float*)d_in[3];
    const float* wihf   = (const float*)d_in[4];
    const float* whhf   = (const float*)d_in[5];
    const float* bf     = (const float*)d_in[6];
    const float* wihb   = (const float*)d_in[7];
    const float* whhb   = (const float*)d_in[8];
    const float* bbv    = (const float*)d_in[9];
    const float* wem    = (const float*)d_in[10];
    const float* bem    = (const float*)d_in[11];
    const float* trans  = (const float*)d_in[12];
    float* out = (float*)d_out;

    char* p = (char*)d_ws;
    auto take = [&](size_t bytes) -> char* {
        char* q = p;
        p += (bytes + 255) & ~(size_t)255;
        return q;
    };
    u16* xw_f   = (u16*)take((size_t)Sn * Bn * G4 * 2);   // 64 MB
    u16* xw_b   = (u16*)take((size_t)Sn * Bn * G4 * 2);   // 64 MB
    u16* hf     = (u16*)take((size_t)Bn * Sn * Hn * 2);   // 16 MB, layout [b][t][k]
    u16* hb     = (u16*)take((size_t)Bn * Sn * Hn * 2);   // 16 MB, layout [b][t][k]
    u16* xbf    = (u16*)take((size_t)Bn * Sn * En * 2);   // 8 MB
    u16* wihf_b = (u16*)take((size_t)G4 * En * 2);
    u16* wihb_b = (u16*)take((size_t)G4 * En * 2);
    u16* whhf_b = (u16*)take((size_t)G4 * Hn * 2);
    u16* whhb_b = (u16*)take((size_t)G4 * Hn * 2);
    u16* wem_b  = (u16*)take((size_t)Ln * 2 * Hn * 2);
    float* e        = (float*)take((size_t)Bn * Sn * Ln * 4);
    float* expT     = (float*)take((size_t)Ln * Ln * 4);
    float* alphaAcc = (float*)take((size_t)Bn * Ln * 4);
    float* realAcc  = (float*)take((size_t)Bn * 4);
    if ((size_t)(p - (char*)d_ws) > ws_size) return;

    prep_kernel<<<4096, 256, 0, stream>>>(tokens, embed, wihf, wihb, whhf, whhb, wem, trans,
                                          xbf, wihf_b, wihb_b, whhf_b, whhb_b, wem_b,
                                          expT, alphaAcc, realAcc,
                                          (unsigned*)hf, (unsigned*)hb);

    dim3 g1(256, 32, 2);
    gemm_xw<<<g1, 256, 0, stream>>>(xbf, wihf_b, wihb_b, bf, bbv, xw_f, xw_b);

    void* ra[] = { (void*)&whhf_b, (void*)&whhb_b, (void*)&xw_f, (void*)&xw_b,
                   (void*)&hf, (void*)&hb };
    hipLaunchCooperativeKernel((const void*)lstm_rec, dim3(2 * NWG), dim3(512), ra, 0, stream);

    emis<<<256, 256, 0, stream>>>(hf, hb, wem_b, bem, e);
    crf_step<<<Bn * Sn, 64, 0, stream>>>(e, expT, labels, length, alphaAcc, realAcc);
    finalize<<<1, 64, 0, stream>>>(e, alphaAcc, realAcc, out);
}

// Round 11
// 1801.190 us; speedup vs baseline: 2.0814x; 1.0647x over previous
//
#include <hip/hip_runtime.h>
#include <math.h>
#include <stdint.h>

// Problem constants
#define Bn 32
#define Sn 512
#define En 256
#define Hn 512
#define Ln 48
#define G4 2048   // 4*H
#define NWG 32    // workgroups per direction in lstm_rec
#define SENT16 0x7FFFu   // bf16 NaN — impossible for h = o*tanh(c), |h|<1

typedef unsigned short u16;
typedef __attribute__((ext_vector_type(8))) __bf16 bf16x8;
typedef __attribute__((ext_vector_type(4))) float f32x4;

__device__ inline float bf2f(u16 u) {
    return __uint_as_float(((unsigned)u) << 16);
}
__device__ inline u16 f2bf(float f) {
    unsigned u = __float_as_uint(f);
    unsigned r = (u + 0x7fffu + ((u >> 16) & 1u)) >> 16;  // RTNE
    return (u16)r;
}
__device__ inline float sigmoidf_(float x) { return 1.f / (1.f + expf(-x)); }
__device__ inline float tanh_fast(float x) { return 2.f / (1.f + expf(-2.f * x)) - 1.f; }

// any 16-bit field of the 4 dwords equals SENT16?
__device__ inline unsigned badMask(f32x4 v) {
    unsigned acc = 0;
    #pragma unroll
    for (int i = 0; i < 4; i++) {
        unsigned d = __float_as_uint(v[i]);
        unsigned x = d ^ 0x7FFF7FFFu;
        acc |= (x - 0x00010001u) & ~x & 0x80008000u;
    }
    return acc;
}

// ---------------------------------------------------------------------------
// prep: embed gather -> bf16 x, weight bf16 conversions, exp(T), zero accums,
// sentinel-fill h buffers
// ---------------------------------------------------------------------------
__global__ __launch_bounds__(256) void prep_kernel(
    const int* __restrict__ tokens, const float* __restrict__ embed,
    const float* __restrict__ wihf, const float* __restrict__ wihb,
    const float* __restrict__ whhf, const float* __restrict__ whhb,
    const float* __restrict__ wem, const float* __restrict__ trans,
    u16* __restrict__ xbf, u16* __restrict__ wihf_b, u16* __restrict__ wihb_b,
    u16* __restrict__ whhf_b, u16* __restrict__ whhb_b, u16* __restrict__ wem_b,
    float* __restrict__ expT, float* __restrict__ alphaAcc,
    float* __restrict__ realAcc, unsigned* __restrict__ hf32,
    unsigned* __restrict__ hb32)
{
    size_t idx = (size_t)blockIdx.x * blockDim.x + threadIdx.x;
    size_t stride = (size_t)gridDim.x * blockDim.x;
    for (size_t i = idx; i < (size_t)Bn * Sn * En; i += stride) {
        size_t n = i >> 8; int ee = (int)(i & 255);
        int tok = tokens[n];
        xbf[i] = f2bf(embed[(size_t)tok * En + ee]);
    }
    for (size_t i = idx; i < (size_t)G4 * En; i += stride) {
        wihf_b[i] = f2bf(wihf[i]); wihb_b[i] = f2bf(wihb[i]);
    }
    for (size_t i = idx; i < (size_t)G4 * Hn; i += stride) {
        whhf_b[i] = f2bf(whhf[i]); whhb_b[i] = f2bf(whhb[i]);
    }
    for (size_t i = idx; i < (size_t)Ln * 2 * Hn; i += stride) wem_b[i] = f2bf(wem[i]);
    for (size_t i = idx; i < (size_t)Ln * Ln; i += stride) expT[i] = expf(trans[i]);
    for (size_t i = idx; i < (size_t)Bn * Ln; i += stride) alphaAcc[i] = 0.f;
    for (size_t i = idx; i < (size_t)Bn; i += stride) realAcc[i] = 0.f;
    const unsigned sp = (SENT16 << 16) | SENT16;
    for (size_t i = idx; i < (size_t)Bn * Sn * Hn / 2; i += stride) {
        hf32[i] = sp; hb32[i] = sp;
    }
}

// ---------------------------------------------------------------------------
// gemm_xw: xw[dir][t][b][g] = x(b,t) . w_ih[g] + bias[g], bf16 MFMA, fp32 acc
// 128x128 tile, 256 thr (4 waves, each 64x64 via 4x4 of 16x16), BK=64,
// LDS rows padded +8 u16 (2-way banks = free).
// ---------------------------------------------------------------------------
__global__ __launch_bounds__(256) void gemm_xw(
    const u16* __restrict__ xbf, const u16* __restrict__ wihf_b,
    const u16* __restrict__ wihb_b, const float* __restrict__ bias_f,
    const float* __restrict__ bias_b, u16* __restrict__ xw_f, u16* __restrict__ xw_b)
{
    int mb = blockIdx.x, nb = blockIdx.y, dir = blockIdx.z;
    const u16* wih = dir ? wihb_b : wihf_b;
    const float* bias = dir ? bias_b : bias_f;
    u16* xw = dir ? xw_b : xw_f;

    __shared__ u16 As[128 * 72];   // 128 rows x 64 k, pad 8
    __shared__ u16 Bs[128 * 72];

    int tid = threadIdx.x;
    int w = tid >> 6, lane = tid & 63;
    int lm = lane & 15, kq = lane >> 4;
    int Moff = (w & 1) * 64, Noff = (w >> 1) * 64;

    f32x4 zero = {0.f, 0.f, 0.f, 0.f};
    f32x4 acc[4][4];
    #pragma unroll
    for (int mi = 0; mi < 4; mi++)
        #pragma unroll
        for (int ni = 0; ni < 4; ni++) acc[mi][ni] = zero;

    for (int kc = 0; kc < 4; kc++) {
        #pragma unroll
        for (int it = 0; it < 4; it++) {
            int idx = tid + it * 256;
            int r = idx >> 3, pos = (idx & 7) * 8;
            *(bf16x8*)&As[r * 72 + pos] =
                *(const bf16x8*)&xbf[((size_t)(mb * 128 + r)) * En + kc * 64 + pos];
            *(bf16x8*)&Bs[r * 72 + pos] =
                *(const bf16x8*)&wih[((size_t)(nb * 128 + r)) * En + kc * 64 + pos];
        }
        __syncthreads();
        #pragma unroll
        for (int ks = 0; ks < 2; ks++) {
            int k = ks * 32 + kq * 8;
            bf16x8 af[4], bfr[4];
            #pragma unroll
            for (int mi = 0; mi < 4; mi++)
                af[mi] = *(const bf16x8*)&As[(Moff + mi * 16 + lm) * 72 + k];
            #pragma unroll
            for (int ni = 0; ni < 4; ni++)
                bfr[ni] = *(const bf16x8*)&Bs[(Noff + ni * 16 + lm) * 72 + k];
            #pragma unroll
            for (int mi = 0; mi < 4; mi++)
                #pragma unroll
                for (int ni = 0; ni < 4; ni++)
                    acc[mi][ni] = __builtin_amdgcn_mfma_f32_16x16x32_bf16(
                        af[mi], bfr[ni], acc[mi][ni], 0, 0, 0);
        }
        __syncthreads();
    }
    #pragma unroll
    for (int mi = 0; mi < 4; mi++)
        #pragma unroll
        for (int ni = 0; ni < 4; ni++)
            #pragma unroll
            for (int reg = 0; reg < 4; reg++) {
                int row = Moff + mi * 16 + kq * 4 + reg;
                int col = Noff + ni * 16 + lm;
                int n = mb * 128 + row;          // n = b*512 + t
                int g = nb * 128 + col;
                int t = n & 511, b = n >> 9;
                float v = acc[mi][ni][reg] + bias[g];
                xw[((size_t)t * Bn + b) * G4 + g] = f2bf(v);
            }
}

// ---------------------------------------------------------------------------
// lstm_rec: 64 WGs (32/dir) x 512 thr, cooperative. R8 verified config:
// sc1 device-scope data-poll with sentinel retry, LDS staging, batched
// 64x16B producer stores. ~3.0 us/step latency floor.
// ---------------------------------------------------------------------------
__global__ __launch_bounds__(512) void lstm_rec(
    const u16* __restrict__ whhf_b, const u16* __restrict__ whhb_b,
    const u16* __restrict__ xw_f, const u16* __restrict__ xw_b,
    u16* __restrict__ hf, u16* __restrict__ hb)
{
    int wg = blockIdx.x;
    int dir = wg >> 5;
    int w = wg & 31;
    const u16* __restrict__ whh = dir ? whhb_b : whhf_b;
    const u16* __restrict__ xw  = dir ? xw_b  : xw_f;
    u16* __restrict__ hbuf = dir ? hb : hf;

    __shared__ u16 Hs[32 * 512];        // h_{t-1} staged, XOR-swizzled chunks
    __shared__ float Cp[4 * 32 * 17];   // gate partials [gate][batch][hcol]
    __shared__ u16 hout[32 * 16];

    int tid = threadIdx.x;
    int wv = tid >> 6, lane = tid & 63;
    int lm = lane & 15, kq = lane >> 4;
    int mt = wv & 1, nt = wv >> 1;       // wave -> (batch-tile, gate)
    int b = tid >> 4, hc = tid & 15;     // gate-phase / staging role

    // B fragments (w_hh rows for gate nt, hidden cols w*16..+16) in registers
    bf16x8 Bf[16];
    {
        const u16* wrow = &whh[((size_t)nt * Hn + (size_t)w * 16 + lm) * Hn];
        #pragma unroll
        for (int ks = 0; ks < 16; ks++)
            Bf[ks] = *(const bf16x8*)&wrow[ks * 32 + kq * 8];
    }

    float c_state = 0.f;
    const f32x4 zero = {0.f, 0.f, 0.f, 0.f};

    for (int it = 0; it < Sn; it++) {
        int t = dir ? (Sn - 1 - it) : it;
        f32x4 acc = zero;

        // xw gate inputs for (b, hc) — independent of h; issue before the poll
        const u16* xp = &xw[((size_t)t * Bn + b) * G4 + (size_t)w * 16 + hc];
        float xg0 = bf2f(xp[0 * Hn]);
        float xg1 = bf2f(xp[1 * Hn]);
        float xg2 = bf2f(xp[2 * Hn]);
        float xg3 = bf2f(xp[3 * Hn]);

        if (it > 0) {
            int tprev = dir ? (t + 1) : (t - 1);
            const u16* base = &hbuf[((size_t)b * Sn + tprev) * Hn];
            const u16* p0 = base + (hc + 0) * 8;
            const u16* p1 = base + (hc + 16) * 8;
            const u16* p2 = base + (hc + 32) * 8;
            const u16* p3 = base + (hc + 48) * 8;
            f32x4 h0, h1, h2, h3;
            int tries = 0;
            while (true) {
                asm volatile(
                    "global_load_dwordx4 %0, %4, off sc1\n\t"
                    "global_load_dwordx4 %1, %5, off sc1\n\t"
                    "global_load_dwordx4 %2, %6, off sc1\n\t"
                    "global_load_dwordx4 %3, %7, off sc1\n\t"
                    "s_waitcnt vmcnt(0)"
                    : "=v"(h0), "=v"(h1), "=v"(h2), "=v"(h3)
                    : "v"(p0), "v"(p1), "v"(p2), "v"(p3)
                    : "memory");
                if (!(badMask(h0) | badMask(h1) | badMask(h2) | badMask(h3))) break;
                if (++tries > (1 << 16)) break;   // fail-safe: never hang
            }
            *(f32x4*)&Hs[(b * 64 + ((hc + 0) ^ (b & 7))) * 8] = h0;
            *(f32x4*)&Hs[(b * 64 + ((hc + 16) ^ (b & 7))) * 8] = h1;
            *(f32x4*)&Hs[(b * 64 + ((hc + 32) ^ (b & 7))) * 8] = h2;
            *(f32x4*)&Hs[(b * 64 + ((hc + 48) ^ (b & 7))) * 8] = h3;
            __syncthreads();                              // sync #1

            f32x4 aa = zero, ab = zero;
            #pragma unroll
            for (int ks2 = 0; ks2 < 8; ks2++) {
                bf16x8 a0 = *(const bf16x8*)
                    &Hs[((mt * 16 + lm) * 64 + (((2 * ks2) * 4 + kq) ^ (lm & 7))) * 8];
                aa = __builtin_amdgcn_mfma_f32_16x16x32_bf16(a0, Bf[2 * ks2], aa, 0, 0, 0);
                bf16x8 a1 = *(const bf16x8*)
                    &Hs[((mt * 16 + lm) * 64 + (((2 * ks2 + 1) * 4 + kq) ^ (lm & 7))) * 8];
                ab = __builtin_amdgcn_mfma_f32_16x16x32_bf16(a1, Bf[2 * ks2 + 1], ab, 0, 0, 0);
            }
            acc = aa + ab;
        }

        #pragma unroll
        for (int reg = 0; reg < 4; reg++)
            Cp[(nt * 32 + mt * 16 + kq * 4 + reg) * 17 + lm] = acc[reg];
        __syncthreads();                                  // sync #2

        float g0 = Cp[(0 * 32 + b) * 17 + hc] + xg0;
        float g1 = Cp[(1 * 32 + b) * 17 + hc] + xg1;
        float g2 = Cp[(2 * 32 + b) * 17 + hc] + xg2;
        float g3 = Cp[(3 * 32 + b) * 17 + hc] + xg3;
        float i_ = sigmoidf_(g0);
        float f_ = sigmoidf_(g1);
        float gg = tanh_fast(g2);
        float o_ = sigmoidf_(g3);
        c_state = f_ * c_state + i_ * gg;
        float hv = o_ * tanh_fast(c_state);
        hout[tid] = f2bf(hv);
        __syncthreads();                                  // sync #3

        if (tid < 64) {
            int bq = lane >> 1, half = lane & 1;
            f32x4 hv8 = *(const f32x4*)&hout[lane * 8];
            u16* sp = &hbuf[((size_t)bq * Sn + t) * Hn + (size_t)w * 16 + half * 8];
            asm volatile("global_store_dwordx4 %0, %1, off sc1"
                         :: "v"(sp), "v"(hv8) : "memory");
        }
    }
}

// ---------------------------------------------------------------------------
// emis_crf: fused emission GEMM + exp + CRF accumulation. One block per
// (b, 64-t chunk); emission values stay in LDS; per-block partial
// logsumexp sums -> 48 atomics into alphaAcc, real-path terms -> 1 atomic
// into realAcc. Only e[:,0,:] materialized (for finalize).
// ---------------------------------------------------------------------------
__global__ __launch_bounds__(256) void emis_crf(
    const u16* __restrict__ hf, const u16* __restrict__ hb,
    const u16* __restrict__ wem_b, const float* __restrict__ bem,
    const float* __restrict__ expT, const int* __restrict__ labels,
    const int* __restrict__ lengths, float* __restrict__ e0,
    float* __restrict__ alphaAcc, float* __restrict__ realAcc)
{
    int mb = blockIdx.x;                 // 256 blocks
    int b = mb >> 3, t0 = (mb & 7) * 64; // rows mb*64.. are (b, t0..t0+64)

    __shared__ float eL[64][49];
    __shared__ float Ts[48 * 48];
    __shared__ float sred[4][48];
    __shared__ float rred[64];

    int tid = threadIdx.x;
    for (int i = tid; i < 48 * 48; i += 256) Ts[i] = expT[i];

    int wv = tid >> 6, lane = tid & 63;
    int lm = lane & 15, lkq = (lane >> 4) * 8;
    int row = mb * 64 + wv * 16;

    f32x4 zero = {0.f, 0.f, 0.f, 0.f};
    f32x4 acc[3] = {zero, zero, zero};
    for (int ks = 0; ks < 32; ks++) {
        int k = ks * 32 + lkq;
        const u16* hsrc = (ks < 16) ? &hf[(size_t)(row + lm) * Hn + k]
                                    : &hb[(size_t)(row + lm) * Hn + (k - 512)];
        bf16x8 a = *(const bf16x8*)hsrc;
        #pragma unroll
        for (int nt = 0; nt < 3; nt++) {
            bf16x8 bfr = *(const bf16x8*)&wem_b[(size_t)(nt * 16 + lm) * 1024 + k];
            acc[nt] = __builtin_amdgcn_mfma_f32_16x16x32_bf16(a, bfr, acc[nt], 0, 0, 0);
        }
    }
    #pragma unroll
    for (int nt = 0; nt < 3; nt++)
        #pragma unroll
        for (int reg = 0; reg < 4; reg++) {
            int rib = wv * 16 + (lane >> 4) * 4 + reg;   // row in block = t - t0
            int col = nt * 16 + lm;
            float v = expf(acc[nt][reg] + bem[col]);
            eL[rib][col] = v;
            if ((mb & 7) == 0 && rib == 0) e0[b * Ln + col] = v;   // t == 0
        }
    __syncthreads();

    int len = lengths[b];
    if (tid < 192) {
        int i = tid % 48, tg = tid / 48;   // 4 groups x 48 labels
        float sacc = 0.f;
        for (int p = tg * 16; p < tg * 16 + 16; p++) {
            int t = t0 + p;
            if (t >= 1 && t < len) {
                float m = -1e30f;
                for (int j = 0; j < 48; j++) m = fmaxf(m, Ts[i * 48 + j] + eL[p][j]);
                float s = 0.f;
                for (int j = 0; j < 48; j++) s += expf(Ts[i * 48 + j] + eL[p][j] - m);
                sacc += m + logf(s);
            }
        }
        sred[tg][i] = sacc;
    } else {
        int p = tid - 192;                  // 0..63
        int t = t0 + p;
        float r = 0.f;
        if (t < len) {
            int lab = labels[b * Sn + t];
            r = eL[p][lab];
            if (t >= 1) r += Ts[labels[b * Sn + t - 1] * 48 + lab];
        }
        rred[p] = r;
    }
    __syncthreads();
    if (tid < 48) {
        float s = sred[0][tid] + sred[1][tid] + sred[2][tid] + sred[3][tid];
        atomicAdd(&alphaAcc[b * Ln + tid], s);
    } else if (tid == 48) {
        float r = 0.f;
        for (int p = 0; p < 64; p++) r += rred[p];
        atomicAdd(&realAcc[b], r);
    }
}

__global__ __launch_bounds__(64) void finalize(
    const float* __restrict__ e0, const float* __restrict__ alphaAcc,
    const float* __restrict__ realAcc, float* __restrict__ out)
{
    int b = threadIdx.x;
    if (b >= Bn) return;
    float m = -1e30f;
    for (int i = 0; i < Ln; i++) {
        float a = e0[b * Ln + i] + alphaAcc[b * Ln + i];
        m = fmaxf(m, a);
    }
    float s = 0.f;
    for (int i = 0; i < Ln; i++) {
        float a = e0[b * Ln + i] + alphaAcc[b * Ln + i];
        s += expf(a - m);
    }
    out[b] = m + logf(s) - realAcc[b];
}

// ---------------------------------------------------------------------------
extern "C" void kernel_launch(void* const* d_in, const int* in_sizes, int n_in,
                              void* d_out, int out_size, void* d_ws, size_t ws_size,
                              hipStream_t stream)
{
    const int*   tokens = (const int*)d_in[0];
    const int*   length = (const int*)d_in[1];
    const int*   labels = (const int*)d_in[2];
    const float* embed  = (const float*)d_in[3];
    const float* wihf   = (const float*)d_in[4];
    const float* whhf   = (const float*)d_in[5];
    const float* bf     = (const float*)d_in[6];
    const float* wihb   = (const float*)d_in[7];
    const float* whhb   = (const float*)d_in[8];
    const float* bbv    = (const float*)d_in[9];
    const float* wem    = (const float*)d_in[10];
    const float* bem    = (const float*)d_in[11];
    const float* trans  = (const float*)d_in[12];
    float* out = (float*)d_out;

    char* p = (char*)d_ws;
    auto take = [&](size_t bytes) -> char* {
        char* q = p;
        p += (bytes + 255) & ~(size_t)255;
        return q;
    };
    u16* xw_f   = (u16*)take((size_t)Sn * Bn * G4 * 2);   // 64 MB
    u16* xw_b   = (u16*)take((size_t)Sn * Bn * G4 * 2);   // 64 MB
    u16* hf     = (u16*)take((size_t)Bn * Sn * Hn * 2);   // 16 MB, layout [b][t][k]
    u16* hb     = (u16*)take((size_t)Bn * Sn * Hn * 2);   // 16 MB, layout [b][t][k]
    u16* xbf    = (u16*)take((size_t)Bn * Sn * En * 2);   // 8 MB
    u16* wihf_b = (u16*)take((size_t)G4 * En * 2);
    u16* wihb_b = (u16*)take((size_t)G4 * En * 2);
    u16* whhf_b = (u16*)take((size_t)G4 * Hn * 2);
    u16* whhb_b = (u16*)take((size_t)G4 * Hn * 2);
    u16* wem_b  = (u16*)take((size_t)Ln * 2 * Hn * 2);
    float* expT     = (float*)take((size_t)Ln * Ln * 4);
    float* e0       = (float*)take((size_t)Bn * Ln * 4);
    float* alphaAcc = (float*)take((size_t)Bn * Ln * 4);
    float* realAcc  = (float*)take((size_t)Bn * 4);
    if ((size_t)(p - (char*)d_ws) > ws_size) return;

    prep_kernel<<<4096, 256, 0, stream>>>(tokens, embed, wihf, wihb, whhf, whhb, wem, trans,
                                          xbf, wihf_b, wihb_b, whhf_b, whhb_b, wem_b,
                                          expT, alphaAcc, realAcc,
                                          (unsigned*)hf, (unsigned*)hb);

    dim3 g1(128, 16, 2);
    gemm_xw<<<g1, 256, 0, stream>>>(xbf, wihf_b, wihb_b, bf, bbv, xw_f, xw_b);

    void* ra[] = { (void*)&whhf_b, (void*)&whhb_b, (void*)&xw_f, (void*)&xw_b,
                   (void*)&hf, (void*)&hb };
    hipLaunchCooperativeKernel((const void*)lstm_rec, dim3(2 * NWG), dim3(512), ra, 0, stream);

    emis_crf<<<256, 256, 0, stream>>>(hf, hb, wem_b, bem, expT, labels, length,
                                      e0, alphaAcc, realAcc);
    finalize<<<1, 64, 0, stream>>>(e0, alphaAcc, realAcc, out);
}